// Round 3
// baseline (1816.796 us; speedup 1.0000x reference)
//
#include <hip/hip_runtime.h>
#include <math.h>

#define D   128
#define ED  16
#define LAYERS 3
#define CLS 10
#define NPB 8          // nodes per block in aggregate_kernel

// ===========================================================================
// Preprocessing: build CSR (edges grouped by dst) once per launch.
// Note: scatter order within a dst segment is atomic-arrival order (non-
// deterministic) — only affects fp sum ORDER (~1e-6 rel), not the value set.
// ===========================================================================
__global__ __launch_bounds__(256) void hist_kernel(
    const int* __restrict__ dst, int* __restrict__ deg, int E)
{
    for (int e = blockIdx.x * blockDim.x + threadIdx.x; e < E;
         e += gridDim.x * blockDim.x)
        atomicAdd(&deg[dst[e]], 1);
}

// single-block exclusive scan: deg[N] -> row_ptr[N+1], cursor[N]
__global__ __launch_bounds__(256) void scan_kernel(
    const int* __restrict__ deg, int* __restrict__ row_ptr,
    int* __restrict__ cursor, int N)
{
    __shared__ int part[256];
    const int t = threadIdx.x;
    const int chunk = (N + 255) / 256;
    const int beg = t * chunk;
    const int end = min(beg + chunk, N);

    int s = 0;
    for (int i = beg; i < end; ++i) s += deg[i];
    part[t] = s;
    __syncthreads();
    for (int ofs = 1; ofs < 256; ofs <<= 1) {
        int v = (t >= ofs) ? part[t - ofs] : 0;
        __syncthreads();
        part[t] += v;
        __syncthreads();
    }
    int base = (t == 0) ? 0 : part[t - 1];
    for (int i = beg; i < end; ++i) {
        row_ptr[i] = base;
        cursor[i]  = base;
        base += deg[i];
    }
    if (t == 255) row_ptr[N] = part[255];
}

__global__ __launch_bounds__(256) void scatter_kernel(
    const int* __restrict__ src, const int* __restrict__ dst,
    const float* __restrict__ ea,
    int* __restrict__ cursor,
    int* __restrict__ src_s, float* __restrict__ ea_s, int E)
{
    for (int e = blockIdx.x * blockDim.x + threadIdx.x; e < E;
         e += gridDim.x * blockDim.x) {
        const int pos = atomicAdd(&cursor[dst[e]], 1);
        src_s[pos] = src[e];
        const float4* a = (const float4*)(ea + (size_t)e * ED);
        float4* o = (float4*)(ea_s + (size_t)pos * ED);
        o[0] = a[0]; o[1] = a[1]; o[2] = a[2]; o[3] = a[3];
    }
}

// ===========================================================================
// Atomic-free aggregation: z[n] = h[n] + sum_{e in csr(n)} relu(h[src]+ea@We+be)
// 128 threads (thread = channel), NPB nodes serial per block.
// 2-deep software pipeline (next edge's ea row + h gather issued before the
// current edge's FMAs) + 4 independent partial dot sums (breaks the 16-FMA
// dependency chain).
// ===========================================================================
__global__ __launch_bounds__(128) void aggregate_kernel(
    const float* __restrict__ h,
    const float* __restrict__ ea_s,
    const int*   __restrict__ src_s,
    const int*   __restrict__ row_ptr,
    const float* __restrict__ We,   // [16][128] this layer
    const float* __restrict__ be,
    float* __restrict__ z, int N)
{
    const int d = threadIdx.x;
    float w[ED];
#pragma unroll
    for (int k = 0; k < ED; ++k) w[k] = We[k * D + d];
    const float bias = be[d];

    const int nend = min((blockIdx.x + 1) * NPB, N);
    for (int n = blockIdx.x * NPB; n < nend; ++n) {
        const int beg = row_ptr[n];
        const int end = row_ptr[n + 1];
        float acc = h[(size_t)n * D + d];

        if (beg < end) {
            // prologue: load edge `beg`
            const float4* a4 = (const float4*)(ea_s + (size_t)beg * ED);
            float4 a0 = a4[0], a1 = a4[1], a2 = a4[2], a3 = a4[3];
            float  hv = h[(size_t)src_s[beg] * D + d];

            for (int e = beg; e < end; ++e) {
                // ---- issue next edge's loads first (hide gather latency) --
                float4 b0, b1, b2, b3;
                float  hv2 = 0.0f;
                if (e + 1 < end) {
                    const float4* c4 = (const float4*)(ea_s + (size_t)(e + 1) * ED);
                    b0 = c4[0]; b1 = c4[1]; b2 = c4[2]; b3 = c4[3];
                    hv2 = h[(size_t)src_s[e + 1] * D + d];
                } else {
                    b0 = a0; b1 = a1; b2 = a2; b3 = a3;
                }
                // ---- compute current edge: 4 independent partial sums -----
                float m0 = bias + hv;
                float m1 = 0.f, m2 = 0.f, m3 = 0.f;
                m0 += a0.x * w[0];  m1 += a0.y * w[1];  m2 += a0.z * w[2];  m3 += a0.w * w[3];
                m0 += a1.x * w[4];  m1 += a1.y * w[5];  m2 += a1.z * w[6];  m3 += a1.w * w[7];
                m0 += a2.x * w[8];  m1 += a2.y * w[9];  m2 += a2.z * w[10]; m3 += a2.w * w[11];
                m0 += a3.x * w[12]; m1 += a3.y * w[13]; m2 += a3.z * w[14]; m3 += a3.w * w[15];
                acc += fmaxf((m0 + m1) + (m2 + m3), 0.0f);
                // ---- rotate pipeline --------------------------------------
                a0 = b0; a1 = b1; a2 = b2; a3 = b3; hv = hv2;
            }
        }
        z[(size_t)n * D + d] = acc;
    }
}

// ===========================================================================
// Node MLP: h_out = relu( relu(bn(z @ W1 + b1)) @ W2 + b2 )
// 32 nodes x 128 ch per block, 4x4 register tile, swizzled transposed LDS.
// ===========================================================================
__device__ __forceinline__ int sw_slot(int k, int nq) {
    return (nq ^ (k & 7) ^ ((k >> 3) & 7));
}

__global__ __launch_bounds__(256) void node_kernel(
    const float* __restrict__ zbuf,
    const float* __restrict__ W1, const float* __restrict__ b1,
    const float* __restrict__ gamma, const float* __restrict__ beta,
    const float* __restrict__ W2, const float* __restrict__ b2,
    float* __restrict__ hout)
{
    __shared__ __align__(16) float zs[D * 32];
    __shared__ __align__(16) float ts[D * 32];
    __shared__ __align__(16) float ws[32 * D];

    const int t  = threadIdx.x;
    const int n0 = (t & 7) * 4;
    const int d0 = (t >> 3) * 4;
    const int nb = blockIdx.x * 32;

    const float rstd = 1.0f / sqrtf(1.0f + 1e-5f);
    float4 scv, biv, b2v;
    {
        float4 g4  = *(const float4*)(gamma + d0);
        float4 be4 = *(const float4*)(beta + d0);
        float4 b14 = *(const float4*)(b1 + d0);
        scv.x = rstd * g4.x; scv.y = rstd * g4.y; scv.z = rstd * g4.z; scv.w = rstd * g4.w;
        biv.x = b14.x * scv.x + be4.x; biv.y = b14.y * scv.y + be4.y;
        biv.z = b14.z * scv.z + be4.z; biv.w = b14.w * scv.w + be4.w;
        b2v = *(const float4*)(b2 + d0);
    }

    {
        const float4* zg = (const float4*)(zbuf + (size_t)nb * D);
#pragma unroll
        for (int j = 0; j < 4; ++j) {
            float4 v = zg[t + 256 * j];
            int n = (t + 256 * j) >> 5;
            int k = (t << 2) & 127;
            zs[(k + 0) * 32 + sw_slot(k + 0, n >> 2) * 4 + (n & 3)] = v.x;
            zs[(k + 1) * 32 + sw_slot(k + 1, n >> 2) * 4 + (n & 3)] = v.y;
            zs[(k + 2) * 32 + sw_slot(k + 2, n >> 2) * 4 + (n & 3)] = v.z;
            zs[(k + 3) * 32 + sw_slot(k + 3, n >> 2) * 4 + (n & 3)] = v.w;
        }
    }

    float4 acc[4];
#pragma unroll
    for (int i = 0; i < 4; ++i) acc[i] = make_float4(0.f, 0.f, 0.f, 0.f);

#pragma unroll
    for (int kk = 0; kk < 4; ++kk) {
        __syncthreads();
        {
            const float4* wsrc = (const float4*)(W1 + kk * 32 * D);
            float4* wdst = (float4*)ws;
#pragma unroll
            for (int j = 0; j < 4; ++j) wdst[t + 256 * j] = wsrc[t + 256 * j];
        }
        __syncthreads();
#pragma unroll
        for (int k = 0; k < 32; ++k) {
            const int kg = kk * 32 + k;
            float4 zv = *(const float4*)&zs[kg * 32 + sw_slot(kg, n0 >> 2) * 4];
            float4 wv = *(const float4*)&ws[k * D + d0];
            acc[0].x += zv.x * wv.x; acc[0].y += zv.x * wv.y; acc[0].z += zv.x * wv.z; acc[0].w += zv.x * wv.w;
            acc[1].x += zv.y * wv.x; acc[1].y += zv.y * wv.y; acc[1].z += zv.y * wv.z; acc[1].w += zv.y * wv.w;
            acc[2].x += zv.z * wv.x; acc[2].y += zv.z * wv.y; acc[2].z += zv.z * wv.z; acc[2].w += zv.z * wv.w;
            acc[3].x += zv.w * wv.x; acc[3].y += zv.w * wv.y; acc[3].z += zv.w * wv.z; acc[3].w += zv.w * wv.w;
        }
    }

#pragma unroll
    for (int i = 0; i < 4; ++i) {
        float4 v;
        v.x = fmaxf(acc[i].x * scv.x + biv.x, 0.f);
        v.y = fmaxf(acc[i].y * scv.y + biv.y, 0.f);
        v.z = fmaxf(acc[i].z * scv.z + biv.z, 0.f);
        v.w = fmaxf(acc[i].w * scv.w + biv.w, 0.f);
        acc[i] = v;
    }
    __syncthreads();
#pragma unroll
    for (int j = 0; j < 4; ++j) {
        float4 v;
        v.x = j == 0 ? acc[0].x : j == 1 ? acc[0].y : j == 2 ? acc[0].z : acc[0].w;
        v.y = j == 0 ? acc[1].x : j == 1 ? acc[1].y : j == 2 ? acc[1].z : acc[1].w;
        v.z = j == 0 ? acc[2].x : j == 1 ? acc[2].y : j == 2 ? acc[2].z : acc[2].w;
        v.w = j == 0 ? acc[3].x : j == 1 ? acc[3].y : j == 2 ? acc[3].z : acc[3].w;
        const int kr = d0 + j;
        *(float4*)&ts[kr * 32 + sw_slot(kr, n0 >> 2) * 4] = v;
    }

#pragma unroll
    for (int i = 0; i < 4; ++i) acc[i] = make_float4(0.f, 0.f, 0.f, 0.f);

#pragma unroll
    for (int kk = 0; kk < 4; ++kk) {
        __syncthreads();
        {
            const float4* wsrc = (const float4*)(W2 + kk * 32 * D);
            float4* wdst = (float4*)ws;
#pragma unroll
            for (int j = 0; j < 4; ++j) wdst[t + 256 * j] = wsrc[t + 256 * j];
        }
        __syncthreads();
#pragma unroll
        for (int k = 0; k < 32; ++k) {
            const int kg = kk * 32 + k;
            float4 zv = *(const float4*)&ts[kg * 32 + sw_slot(kg, n0 >> 2) * 4];
            float4 wv = *(const float4*)&ws[k * D + d0];
            acc[0].x += zv.x * wv.x; acc[0].y += zv.x * wv.y; acc[0].z += zv.x * wv.z; acc[0].w += zv.x * wv.w;
            acc[1].x += zv.y * wv.x; acc[1].y += zv.y * wv.y; acc[1].z += zv.y * wv.z; acc[1].w += zv.y * wv.w;
            acc[2].x += zv.z * wv.x; acc[2].y += zv.z * wv.y; acc[2].z += zv.z * wv.z; acc[2].w += zv.z * wv.w;
            acc[3].x += zv.w * wv.x; acc[3].y += zv.w * wv.y; acc[3].z += zv.w * wv.z; acc[3].w += zv.w * wv.w;
        }
    }

#pragma unroll
    for (int i = 0; i < 4; ++i) {
        float4 v;
        v.x = fmaxf(acc[i].x + b2v.x, 0.f);
        v.y = fmaxf(acc[i].y + b2v.y, 0.f);
        v.z = fmaxf(acc[i].z + b2v.z, 0.f);
        v.w = fmaxf(acc[i].w + b2v.w, 0.f);
        *(float4*)&hout[(size_t)(nb + n0 + i) * D + d0] = v;
    }
}

// ===========================================================================
// Pool + classifier (batch sorted -> binary search, atomic-free).
// ===========================================================================
__global__ __launch_bounds__(128) void pool_cls_kernel(
    const float* __restrict__ h,
    const int*   __restrict__ batch,
    const float* __restrict__ Wc1, const float* __restrict__ bc1,
    const float* __restrict__ Wc2, const float* __restrict__ bc2,
    float* __restrict__ out, int N)
{
    const int g = blockIdx.x;
    const int d = threadIdx.x;

    int lo = 0, hi = N;
    while (lo < hi) { int mid = (lo + hi) >> 1; if (batch[mid] < g) lo = mid + 1; else hi = mid; }
    const int start = lo;
    hi = N;
    while (lo < hi) { int mid = (lo + hi) >> 1; if (batch[mid] < g + 1) lo = mid + 1; else hi = mid; }
    const int end = lo;

    float sum = 0.f;
    for (int n = start; n < end; ++n) sum += h[(size_t)n * D + d];

    __shared__ float pooled[D];
    __shared__ float hid[D];
    pooled[d] = sum;
    __syncthreads();

    float acc = bc1[d];
#pragma unroll 8
    for (int k = 0; k < D; ++k) acc += pooled[k] * Wc1[k * D + d];
    hid[d] = fmaxf(acc, 0.f);
    __syncthreads();

    if (d < CLS) {
        float o = bc2[d];
#pragma unroll 8
        for (int j = 0; j < D; ++j) o += hid[j] * Wc2[j * CLS + d];
        out[g * CLS + d] = o;
    }
}

// ===========================================================================
extern "C" void kernel_launch(void* const* d_in, const int* in_sizes, int n_in,
                              void* d_out, int out_size, void* d_ws, size_t ws_size,
                              hipStream_t stream)
{
    const float* x         = (const float*)d_in[0];
    const float* edge_attr = (const float*)d_in[1];
    const float* We        = (const float*)d_in[2];
    const float* be        = (const float*)d_in[3];
    const float* W1        = (const float*)d_in[4];
    const float* b1        = (const float*)d_in[5];
    const float* gamma     = (const float*)d_in[6];
    const float* beta      = (const float*)d_in[7];
    const float* W2        = (const float*)d_in[8];
    const float* b2        = (const float*)d_in[9];
    const float* Wc1       = (const float*)d_in[10];
    const float* bc1       = (const float*)d_in[11];
    const float* Wc2       = (const float*)d_in[12];
    const float* bc2       = (const float*)d_in[13];
    const int*   ei        = (const int*)d_in[14];
    const int*   batch     = (const int*)d_in[15];

    const int N = in_sizes[0] / D;
    const int E = in_sizes[1] / ED;
    const int G = out_size / CLS;

    const int* src = ei;
    const int* dst = ei + E;

    // ---- workspace layout (floats first for 16B alignment) ----
    char* p = (char*)d_ws;
    float* zbuf  = (float*)p;  p += (size_t)N * D * sizeof(float);
    float* hbuf  = (float*)p;  p += (size_t)N * D * sizeof(float);
    float* ea_s  = (float*)p;  p += (size_t)E * ED * sizeof(float);
    int*   src_s = (int*)p;    p += (size_t)E * sizeof(int);
    int*   deg   = (int*)p;    p += (size_t)N * sizeof(int);
    int*   cur   = (int*)p;    p += (size_t)N * sizeof(int);
    int*   rowp  = (int*)p;    p += (size_t)(N + 4) * sizeof(int);
    const size_t need = (size_t)(p - (char*)d_ws);

    if (ws_size >= need) {
        // ================= CSR path (atomic-free aggregation) ==============
        hipMemsetAsync(deg, 0, (size_t)N * sizeof(int), stream);
        hist_kernel<<<1024, 256, 0, stream>>>(dst, deg, E);
        scan_kernel<<<1, 256, 0, stream>>>(deg, rowp, cur, N);
        scatter_kernel<<<2048, 256, 0, stream>>>(src, dst, edge_attr, cur,
                                                 src_s, ea_s, E);

        const float* hcur = x;
        for (int l = 0; l < LAYERS; ++l) {
            aggregate_kernel<<<(N + NPB - 1) / NPB, 128, 0, stream>>>(
                hcur, ea_s, src_s, rowp,
                We + (size_t)l * ED * D, be + (size_t)l * D, zbuf, N);
            node_kernel<<<N / 32, 256, 0, stream>>>(
                zbuf, W1 + (size_t)l * D * D, b1 + (size_t)l * D,
                gamma + (size_t)l * D, beta + (size_t)l * D,
                W2 + (size_t)l * D * D, b2 + (size_t)l * D, hbuf);
            hcur = hbuf;
        }
    } else {
        // ================= fallback: atomic scatter path (no CSR room) =====
        const float* hcur = x;
        for (int l = 0; l < LAYERS; ++l) {
            hipMemcpyAsync(zbuf, hcur, (size_t)N * D * sizeof(float),
                           hipMemcpyDeviceToDevice, stream);
            // reuse aggregate-free path: edge-parallel atomics
            // (grid-stride, 2 edges per 256-thread block)
            // NOTE: kept minimal; CSR path is the expected route.
            extern __global__ void edge_fallback(const float*, const float*,
                                                 const float*, const float*,
                                                 const int*, const int*,
                                                 float*, int);
            // fallthrough handled below by lambda-less direct launch
            // (defined after this function) -- see edge_fallback_kernel
            void* _ = nullptr; (void)_;
            // actual launch:
            {
                extern void launch_edge_fallback(const float*, const float*,
                                                 const float*, const float*,
                                                 const int*, const int*,
                                                 float*, int, hipStream_t);
                launch_edge_fallback(hcur, edge_attr,
                                     We + (size_t)l * ED * D, be + (size_t)l * D,
                                     src, dst, zbuf, E, stream);
            }
            node_kernel<<<N / 32, 256, 0, stream>>>(
                zbuf, W1 + (size_t)l * D * D, b1 + (size_t)l * D,
                gamma + (size_t)l * D, beta + (size_t)l * D,
                W2 + (size_t)l * D * D, b2 + (size_t)l * D, hbuf);
            hcur = hbuf;
        }
    }

    pool_cls_kernel<<<G, 128, 0, stream>>>(
        hbuf, batch, Wc1, bc1, Wc2, bc2, (float*)d_out, N);
}

// ---- fallback edge kernel + launcher (atomic path) ------------------------
__global__ __launch_bounds__(256) void edge_fallback_kernel(
    const float* __restrict__ h,
    const float* __restrict__ ea,
    const float* __restrict__ We,
    const float* __restrict__ be,
    const int*   __restrict__ src,
    const int*   __restrict__ dst,
    float* __restrict__ zbuf,
    int E)
{
    const int d   = threadIdx.x & 127;
    const int sub = threadIdx.x >> 7;
    float w[ED];
#pragma unroll
    for (int k = 0; k < ED; ++k) w[k] = We[k * D + d];
    const float bias = be[d];

    for (int e = blockIdx.x * 2 + sub; e < E; e += gridDim.x * 2) {
        const float4* a4 = (const float4*)(ea + (size_t)e * ED);
        float4 a0 = a4[0], a1 = a4[1], a2 = a4[2], a3 = a4[3];
        const int s = src[e];
        const int t = dst[e];
        float m0 = bias + h[(size_t)s * D + d];
        float m1 = 0.f, m2 = 0.f, m3 = 0.f;
        m0 += a0.x * w[0];  m1 += a0.y * w[1];  m2 += a0.z * w[2];  m3 += a0.w * w[3];
        m0 += a1.x * w[4];  m1 += a1.y * w[5];  m2 += a1.z * w[6];  m3 += a1.w * w[7];
        m0 += a2.x * w[8];  m1 += a2.y * w[9];  m2 += a2.z * w[10]; m3 += a2.w * w[11];
        m0 += a3.x * w[12]; m1 += a3.y * w[13]; m2 += a3.z * w[14]; m3 += a3.w * w[15];
        atomicAdd(&zbuf[(size_t)t * D + d], fmaxf((m0 + m1) + (m2 + m3), 0.0f));
    }
}

extern "C" void launch_edge_fallback(const float* h, const float* ea,
                                     const float* We, const float* be,
                                     const int* src, const int* dst,
                                     float* zbuf, int E, hipStream_t stream)
{
    edge_fallback_kernel<<<2048, 256, 0, stream>>>(h, ea, We, be, src, dst,
                                                   zbuf, E);
}

// Round 4
// 1665.640 us; speedup vs baseline: 1.0907x; 1.0907x over previous
//
#include <hip/hip_runtime.h>
#include <math.h>

#define D   128
#define ED  16
#define LAYERS 3
#define CLS 10
#define NPB 8          // nodes per block in aggregate_kernel
#define CH  32         // edges per staged chunk

// ===========================================================================
// Preprocessing: build CSR (edges grouped by dst) once per launch.
// ===========================================================================
__global__ __launch_bounds__(256) void hist_kernel(
    const int* __restrict__ dst, int* __restrict__ deg, int E)
{
    for (int e = blockIdx.x * blockDim.x + threadIdx.x; e < E;
         e += gridDim.x * blockDim.x)
        atomicAdd(&deg[dst[e]], 1);
}

__global__ __launch_bounds__(256) void scan_kernel(
    const int* __restrict__ deg, int* __restrict__ row_ptr,
    int* __restrict__ cursor, int N)
{
    __shared__ int part[256];
    const int t = threadIdx.x;
    const int chunk = (N + 255) / 256;
    const int beg = t * chunk;
    const int end = min(beg + chunk, N);

    int s = 0;
    for (int i = beg; i < end; ++i) s += deg[i];
    part[t] = s;
    __syncthreads();
    for (int ofs = 1; ofs < 256; ofs <<= 1) {
        int v = (t >= ofs) ? part[t - ofs] : 0;
        __syncthreads();
        part[t] += v;
        __syncthreads();
    }
    int base = (t == 0) ? 0 : part[t - 1];
    for (int i = beg; i < end; ++i) {
        row_ptr[i] = base;
        cursor[i]  = base;
        base += deg[i];
    }
    if (t == 255) row_ptr[N] = part[255];
}

__global__ __launch_bounds__(256) void scatter_kernel(
    const int* __restrict__ src, const int* __restrict__ dst,
    const float* __restrict__ ea,
    int* __restrict__ cursor,
    int* __restrict__ src_s, float* __restrict__ ea_s, int E)
{
    for (int e = blockIdx.x * blockDim.x + threadIdx.x; e < E;
         e += gridDim.x * blockDim.x) {
        const int pos = atomicAdd(&cursor[dst[e]], 1);
        src_s[pos] = src[e];
        const float4* a = (const float4*)(ea + (size_t)e * ED);
        float4* o = (float4*)(ea_s + (size_t)pos * ED);
        o[0] = a[0]; o[1] = a[1]; o[2] = a[2]; o[3] = a[3];
    }
}

// ===========================================================================
// Aggregation: z[n] = h[n] + sum_{e in csr(n)} relu(h[src]+ea@We+be)
// Latency-hiding structure:
//   - ea rows DMA-staged to per-wave LDS (global_load_lds w16), double-buffered
//     32-edge chunks; NO __syncthreads (waves read only their own region).
//   - counted s_waitcnt vmcnt(2): the 2 newest VMEM ops at the wait are always
//     the just-issued stage ops (sched_barrier pins order) -> chunk c proven
//     landed; everything older (prev staging, h ring, stores) force-drained.
//   - h[src] gather ring 4 deep + src lookahead 3 groups, static reg names.
//   - linear edge walk over the block's NPB nodes, uniform boundary flush.
// ===========================================================================
__device__ __forceinline__ void stage_chunk(
    const float* __restrict__ ea_s, float* ldsbase, long long ce,
    long long Etot, int ln)
{
    const size_t lim = (size_t)Etot * 64 - 16;
#pragma unroll
    for (int i = 0; i < 2; ++i) {
        size_t goff = (size_t)ce * 64 + (size_t)i * 1024 + (size_t)ln * 16;
        if (goff > lim) goff = lim;
        const void* gp = (const char*)ea_s + goff;
        void* lp = (char*)ldsbase + i * 1024;
        __builtin_amdgcn_global_load_lds(
            (const __attribute__((address_space(1))) void*)gp,
            (__attribute__((address_space(3))) void*)lp, 16, 0, 0);
    }
}

__global__ __launch_bounds__(128, 6) void aggregate_kernel(
    const float* __restrict__ h,
    const float* __restrict__ ea_s,
    const int*   __restrict__ src_s,
    const int*   __restrict__ row_ptr,
    const float* __restrict__ We,   // [16][128] this layer
    const float* __restrict__ be,
    float* __restrict__ z, int N, int E)
{
    __shared__ __align__(16) float ealds[2][2][CH * ED]; // [wave][buf][...]
    const int tid = threadIdx.x;
    const int d   = tid;          // channel 0..127
    const int wv  = tid >> 6;     // wave id
    const int ln  = tid & 63;     // lane id

    float w[ED];
#pragma unroll
    for (int k = 0; k < ED; ++k) w[k] = We[k * D + d];
    const float bias = be[d];

    const int n0 = blockIdx.x * NPB;
    const int nN = min(n0 + NPB, N);
    const int E0 = row_ptr[n0];
    const int E1 = row_ptr[nN];

    // uniform walk state
    int   n     = n0;
    int   bound = row_ptr[n0 + 1];
    float agg   = 0.0f;
    float hn    = h[(size_t)n0 * D + d];

    const int ecnt = E1 - E0;
    if (ecnt > 0) {
        const int nc = (ecnt + CH - 1) / CH;
        float* lds0 = &ealds[wv][0][0];
        float* lds1 = &ealds[wv][1][0];

        // ---- prologue ----
        stage_chunk(ea_s, lds0, E0, E, ln);
        // src loads: current group (q=0) + lookahead A(q=1), B(q=2)
        #define LDSRC(q, j) src_s[min(E0 + 4 * (q) + (j), E - 1)]
        int sC0 = LDSRC(0,0), sC1 = LDSRC(0,1), sC2 = LDSRC(0,2), sC3 = LDSRC(0,3);
        int sA0 = LDSRC(1,0), sA1 = LDSRC(1,1), sA2 = LDSRC(1,2), sA3 = LDSRC(1,3);
        int sB0 = LDSRC(2,0), sB1 = LDSRC(2,1), sB2 = LDSRC(2,2), sB3 = LDSRC(2,3);
        asm volatile("s_waitcnt vmcnt(0)" ::: "memory");
        // issue h gathers for group 0
        float hv0 = h[(size_t)sC0 * D + d];
        float hv1 = h[(size_t)sC1 * D + d];
        float hv2 = h[(size_t)sC2 * D + d];
        float hv3 = h[(size_t)sC3 * D + d];

        int eo = E0;   // original edge index (uniform)
        int q  = 0;    // global group counter

        for (int c = 0; c < nc; ++c) {
            // pin order: nothing from previous groups sinks below the stages
            __builtin_amdgcn_sched_barrier(0);
            float* nbuf = ((c + 1) & 1) ? lds1 : lds0;
            stage_chunk(ea_s, nbuf, (long long)E0 + (long long)(c + 1) * CH, E, ln);
            asm volatile("s_waitcnt vmcnt(2)" ::: "memory");
            float* cbuf = (c & 1) ? lds1 : lds0;

#pragma unroll
            for (int g = 0; g < 8; ++g) {
                // (a) prefetch srcs for group q+3
                int t0 = LDSRC(q + 3, 0), t1 = LDSRC(q + 3, 1),
                    t2 = LDSRC(q + 3, 2), t3 = LDSRC(q + 3, 3);
                // (b) issue h gathers for group q+1 (srcs arrived 2 groups ago)
                float f0 = h[(size_t)sA0 * D + d];
                float f1 = h[(size_t)sA1 * D + d];
                float f2 = h[(size_t)sA2 * D + d];
                float f3 = h[(size_t)sA3 * D + d];
                // (c) compute the 4 edges of group q
#pragma unroll
                for (int j = 0; j < 4; ++j) {
                    while (eo == bound) {            // uniform boundary flush
                        z[(size_t)n * D + d] = agg + hn;
                        agg = 0.0f;
                        ++n;
                        if (n >= nN) { bound = 0x7fffffff; }
                        else {
                            bound = row_ptr[n + 1];
                            hn = h[(size_t)n * D + d];
                        }
                    }
                    const float4* ep = (const float4*)&cbuf[(g * 4 + j) * ED];
                    float4 a0 = ep[0], a1 = ep[1], a2 = ep[2], a3 = ep[3];
                    float hvj = (j == 0) ? hv0 : (j == 1) ? hv1 : (j == 2) ? hv2 : hv3;
                    float m0 = bias + hvj;
                    float m1 = 0.f, m2 = 0.f, m3 = 0.f;
                    m0 += a0.x * w[0];  m1 += a0.y * w[1];  m2 += a0.z * w[2];  m3 += a0.w * w[3];
                    m0 += a1.x * w[4];  m1 += a1.y * w[5];  m2 += a1.z * w[6];  m3 += a1.w * w[7];
                    m0 += a2.x * w[8];  m1 += a2.y * w[9];  m2 += a2.z * w[10]; m3 += a2.w * w[11];
                    m0 += a3.x * w[12]; m1 += a3.y * w[13]; m2 += a3.z * w[14]; m3 += a3.w * w[15];
                    float r = fmaxf((m0 + m1) + (m2 + m3), 0.0f);
                    if (eo < E1) agg += r;           // uniform mask (tail)
                    ++eo;
                }
                // (d) rotate rings
                hv0 = f0; hv1 = f1; hv2 = f2; hv3 = f3;
                sA0 = sB0; sA1 = sB1; sA2 = sB2; sA3 = sB3;
                sB0 = t0;  sB1 = t1;  sB2 = t2;  sB3 = t3;
                ++q;
            }
        }
        #undef LDSRC
    }

    // epilogue: flush remaining nodes (incl. zero-degree / last node)
    while (n < nN) {
        z[(size_t)n * D + d] = agg + hn;
        agg = 0.0f;
        ++n;
        if (n < nN) hn = h[(size_t)n * D + d];
    }
}

// ===========================================================================
// Fallback edge kernel (atomic path) if ws too small for CSR buffers.
// ===========================================================================
__global__ __launch_bounds__(256) void edge_fallback_kernel(
    const float* __restrict__ h,
    const float* __restrict__ ea,
    const float* __restrict__ We,
    const float* __restrict__ be,
    const int*   __restrict__ src,
    const int*   __restrict__ dst,
    float* __restrict__ zbuf,
    int E)
{
    const int d   = threadIdx.x & 127;
    const int sub = threadIdx.x >> 7;
    float w[ED];
#pragma unroll
    for (int k = 0; k < ED; ++k) w[k] = We[k * D + d];
    const float bias = be[d];

    for (int e = blockIdx.x * 2 + sub; e < E; e += gridDim.x * 2) {
        const float4* a4 = (const float4*)(ea + (size_t)e * ED);
        float4 a0 = a4[0], a1 = a4[1], a2 = a4[2], a3 = a4[3];
        const int s = src[e];
        const int t = dst[e];
        float m0 = bias + h[(size_t)s * D + d];
        float m1 = 0.f, m2 = 0.f, m3 = 0.f;
        m0 += a0.x * w[0];  m1 += a0.y * w[1];  m2 += a0.z * w[2];  m3 += a0.w * w[3];
        m0 += a1.x * w[4];  m1 += a1.y * w[5];  m2 += a1.z * w[6];  m3 += a1.w * w[7];
        m0 += a2.x * w[8];  m1 += a2.y * w[9];  m2 += a2.z * w[10]; m3 += a2.w * w[11];
        m0 += a3.x * w[12]; m1 += a3.y * w[13]; m2 += a3.z * w[14]; m3 += a3.w * w[15];
        atomicAdd(&zbuf[(size_t)t * D + d], fmaxf((m0 + m1) + (m2 + m3), 0.0f));
    }
}

// ===========================================================================
// Node MLP: h_out = relu( relu(bn(z @ W1 + b1)) @ W2 + b2 )
// 32 nodes x 128 ch per block, 4x4 register tile, swizzled transposed LDS.
// ===========================================================================
__device__ __forceinline__ int sw_slot(int k, int nq) {
    return (nq ^ (k & 7) ^ ((k >> 3) & 7));
}

__global__ __launch_bounds__(256) void node_kernel(
    const float* __restrict__ zbuf,
    const float* __restrict__ W1, const float* __restrict__ b1,
    const float* __restrict__ gamma, const float* __restrict__ beta,
    const float* __restrict__ W2, const float* __restrict__ b2,
    float* __restrict__ hout)
{
    __shared__ __align__(16) float zs[D * 32];
    __shared__ __align__(16) float ts[D * 32];
    __shared__ __align__(16) float ws[32 * D];

    const int t  = threadIdx.x;
    const int n0 = (t & 7) * 4;
    const int d0 = (t >> 3) * 4;
    const int nb = blockIdx.x * 32;

    const float rstd = 1.0f / sqrtf(1.0f + 1e-5f);
    float4 scv, biv, b2v;
    {
        float4 g4  = *(const float4*)(gamma + d0);
        float4 be4 = *(const float4*)(beta + d0);
        float4 b14 = *(const float4*)(b1 + d0);
        scv.x = rstd * g4.x; scv.y = rstd * g4.y; scv.z = rstd * g4.z; scv.w = rstd * g4.w;
        biv.x = b14.x * scv.x + be4.x; biv.y = b14.y * scv.y + be4.y;
        biv.z = b14.z * scv.z + be4.z; biv.w = b14.w * scv.w + be4.w;
        b2v = *(const float4*)(b2 + d0);
    }

    {
        const float4* zg = (const float4*)(zbuf + (size_t)nb * D);
#pragma unroll
        for (int j = 0; j < 4; ++j) {
            float4 v = zg[t + 256 * j];
            int n = (t + 256 * j) >> 5;
            int k = (t << 2) & 127;
            zs[(k + 0) * 32 + sw_slot(k + 0, n >> 2) * 4 + (n & 3)] = v.x;
            zs[(k + 1) * 32 + sw_slot(k + 1, n >> 2) * 4 + (n & 3)] = v.y;
            zs[(k + 2) * 32 + sw_slot(k + 2, n >> 2) * 4 + (n & 3)] = v.z;
            zs[(k + 3) * 32 + sw_slot(k + 3, n >> 2) * 4 + (n & 3)] = v.w;
        }
    }

    float4 acc[4];
#pragma unroll
    for (int i = 0; i < 4; ++i) acc[i] = make_float4(0.f, 0.f, 0.f, 0.f);

#pragma unroll
    for (int kk = 0; kk < 4; ++kk) {
        __syncthreads();
        {
            const float4* wsrc = (const float4*)(W1 + kk * 32 * D);
            float4* wdst = (float4*)ws;
#pragma unroll
            for (int j = 0; j < 4; ++j) wdst[t + 256 * j] = wsrc[t + 256 * j];
        }
        __syncthreads();
#pragma unroll
        for (int k = 0; k < 32; ++k) {
            const int kg = kk * 32 + k;
            float4 zv = *(const float4*)&zs[kg * 32 + sw_slot(kg, n0 >> 2) * 4];
            float4 wv = *(const float4*)&ws[k * D + d0];
            acc[0].x += zv.x * wv.x; acc[0].y += zv.x * wv.y; acc[0].z += zv.x * wv.z; acc[0].w += zv.x * wv.w;
            acc[1].x += zv.y * wv.x; acc[1].y += zv.y * wv.y; acc[1].z += zv.y * wv.z; acc[1].w += zv.y * wv.w;
            acc[2].x += zv.z * wv.x; acc[2].y += zv.z * wv.y; acc[2].z += zv.z * wv.z; acc[2].w += zv.z * wv.w;
            acc[3].x += zv.w * wv.x; acc[3].y += zv.w * wv.y; acc[3].z += zv.w * wv.z; acc[3].w += zv.w * wv.w;
        }
    }

#pragma unroll
    for (int i = 0; i < 4; ++i) {
        float4 v;
        v.x = fmaxf(acc[i].x * scv.x + biv.x, 0.f);
        v.y = fmaxf(acc[i].y * scv.y + biv.y, 0.f);
        v.z = fmaxf(acc[i].z * scv.z + biv.z, 0.f);
        v.w = fmaxf(acc[i].w * scv.w + biv.w, 0.f);
        acc[i] = v;
    }
    __syncthreads();
#pragma unroll
    for (int j = 0; j < 4; ++j) {
        float4 v;
        v.x = j == 0 ? acc[0].x : j == 1 ? acc[0].y : j == 2 ? acc[0].z : acc[0].w;
        v.y = j == 0 ? acc[1].x : j == 1 ? acc[1].y : j == 2 ? acc[1].z : acc[1].w;
        v.z = j == 0 ? acc[2].x : j == 1 ? acc[2].y : j == 2 ? acc[2].z : acc[2].w;
        v.w = j == 0 ? acc[3].x : j == 1 ? acc[3].y : j == 2 ? acc[3].z : acc[3].w;
        const int kr = d0 + j;
        *(float4*)&ts[kr * 32 + sw_slot(kr, n0 >> 2) * 4] = v;
    }

#pragma unroll
    for (int i = 0; i < 4; ++i) acc[i] = make_float4(0.f, 0.f, 0.f, 0.f);

#pragma unroll
    for (int kk = 0; kk < 4; ++kk) {
        __syncthreads();
        {
            const float4* wsrc = (const float4*)(W2 + kk * 32 * D);
            float4* wdst = (float4*)ws;
#pragma unroll
            for (int j = 0; j < 4; ++j) wdst[t + 256 * j] = wsrc[t + 256 * j];
        }
        __syncthreads();
#pragma unroll
        for (int k = 0; k < 32; ++k) {
            const int kg = kk * 32 + k;
            float4 zv = *(const float4*)&ts[kg * 32 + sw_slot(kg, n0 >> 2) * 4];
            float4 wv = *(const float4*)&ws[k * D + d0];
            acc[0].x += zv.x * wv.x; acc[0].y += zv.x * wv.y; acc[0].z += zv.x * wv.z; acc[0].w += zv.x * wv.w;
            acc[1].x += zv.y * wv.x; acc[1].y += zv.y * wv.y; acc[1].z += zv.y * wv.z; acc[1].w += zv.y * wv.w;
            acc[2].x += zv.z * wv.x; acc[2].y += zv.z * wv.y; acc[2].z += zv.z * wv.z; acc[2].w += zv.z * wv.w;
            acc[3].x += zv.w * wv.x; acc[3].y += zv.w * wv.y; acc[3].z += zv.w * wv.z; acc[3].w += zv.w * wv.w;
        }
    }

#pragma unroll
    for (int i = 0; i < 4; ++i) {
        float4 v;
        v.x = fmaxf(acc[i].x + b2v.x, 0.f);
        v.y = fmaxf(acc[i].y + b2v.y, 0.f);
        v.z = fmaxf(acc[i].z + b2v.z, 0.f);
        v.w = fmaxf(acc[i].w + b2v.w, 0.f);
        *(float4*)&hout[(size_t)(nb + n0 + i) * D + d0] = v;
    }
}

// ===========================================================================
// Pool + classifier (batch sorted -> binary search, atomic-free).
// ===========================================================================
__global__ __launch_bounds__(128) void pool_cls_kernel(
    const float* __restrict__ h,
    const int*   __restrict__ batch,
    const float* __restrict__ Wc1, const float* __restrict__ bc1,
    const float* __restrict__ Wc2, const float* __restrict__ bc2,
    float* __restrict__ out, int N)
{
    const int g = blockIdx.x;
    const int d = threadIdx.x;

    int lo = 0, hi = N;
    while (lo < hi) { int mid = (lo + hi) >> 1; if (batch[mid] < g) lo = mid + 1; else hi = mid; }
    const int start = lo;
    hi = N;
    while (lo < hi) { int mid = (lo + hi) >> 1; if (batch[mid] < g + 1) lo = mid + 1; else hi = mid; }
    const int end = lo;

    float sum = 0.f;
    for (int n = start; n < end; ++n) sum += h[(size_t)n * D + d];

    __shared__ float pooled[D];
    __shared__ float hid[D];
    pooled[d] = sum;
    __syncthreads();

    float acc = bc1[d];
#pragma unroll 8
    for (int k = 0; k < D; ++k) acc += pooled[k] * Wc1[k * D + d];
    hid[d] = fmaxf(acc, 0.f);
    __syncthreads();

    if (d < CLS) {
        float o = bc2[d];
#pragma unroll 8
        for (int j = 0; j < D; ++j) o += hid[j] * Wc2[j * CLS + d];
        out[g * CLS + d] = o;
    }
}

// ===========================================================================
extern "C" void kernel_launch(void* const* d_in, const int* in_sizes, int n_in,
                              void* d_out, int out_size, void* d_ws, size_t ws_size,
                              hipStream_t stream)
{
    const float* x         = (const float*)d_in[0];
    const float* edge_attr = (const float*)d_in[1];
    const float* We        = (const float*)d_in[2];
    const float* be        = (const float*)d_in[3];
    const float* W1        = (const float*)d_in[4];
    const float* b1        = (const float*)d_in[5];
    const float* gamma     = (const float*)d_in[6];
    const float* beta      = (const float*)d_in[7];
    const float* W2        = (const float*)d_in[8];
    const float* b2        = (const float*)d_in[9];
    const float* Wc1       = (const float*)d_in[10];
    const float* bc1       = (const float*)d_in[11];
    const float* Wc2       = (const float*)d_in[12];
    const float* bc2       = (const float*)d_in[13];
    const int*   ei        = (const int*)d_in[14];
    const int*   batch     = (const int*)d_in[15];

    const int N = in_sizes[0] / D;
    const int E = in_sizes[1] / ED;
    const int G = out_size / CLS;

    const int* src = ei;
    const int* dst = ei + E;

    // ---- workspace layout (floats first for 16B alignment) ----
    char* p = (char*)d_ws;
    float* zbuf  = (float*)p;  p += (size_t)N * D * sizeof(float);
    float* hbuf  = (float*)p;  p += (size_t)N * D * sizeof(float);
    float* ea_s  = (float*)p;  p += (size_t)E * ED * sizeof(float);
    int*   src_s = (int*)p;    p += (size_t)E * sizeof(int);
    int*   deg   = (int*)p;    p += (size_t)N * sizeof(int);
    int*   cur   = (int*)p;    p += (size_t)N * sizeof(int);
    int*   rowp  = (int*)p;    p += (size_t)(N + 4) * sizeof(int);
    const size_t need = (size_t)(p - (char*)d_ws);

    if (ws_size >= need) {
        // ================= CSR path (atomic-free aggregation) ==============
        hipMemsetAsync(deg, 0, (size_t)N * sizeof(int), stream);
        hist_kernel<<<1024, 256, 0, stream>>>(dst, deg, E);
        scan_kernel<<<1, 256, 0, stream>>>(deg, rowp, cur, N);
        scatter_kernel<<<2048, 256, 0, stream>>>(src, dst, edge_attr, cur,
                                                 src_s, ea_s, E);

        const float* hcur = x;
        for (int l = 0; l < LAYERS; ++l) {
            aggregate_kernel<<<(N + NPB - 1) / NPB, 128, 0, stream>>>(
                hcur, ea_s, src_s, rowp,
                We + (size_t)l * ED * D, be + (size_t)l * D, zbuf, N, E);
            node_kernel<<<N / 32, 256, 0, stream>>>(
                zbuf, W1 + (size_t)l * D * D, b1 + (size_t)l * D,
                gamma + (size_t)l * D, beta + (size_t)l * D,
                W2 + (size_t)l * D * D, b2 + (size_t)l * D, hbuf);
            hcur = hbuf;
        }
    } else {
        // ================= fallback: atomic scatter path ===================
        const float* hcur = x;
        for (int l = 0; l < LAYERS; ++l) {
            hipMemcpyAsync(zbuf, hcur, (size_t)N * D * sizeof(float),
                           hipMemcpyDeviceToDevice, stream);
            edge_fallback_kernel<<<2048, 256, 0, stream>>>(
                hcur, edge_attr, We + (size_t)l * ED * D, be + (size_t)l * D,
                src, dst, zbuf, E);
            node_kernel<<<N / 32, 256, 0, stream>>>(
                zbuf, W1 + (size_t)l * D * D, b1 + (size_t)l * D,
                gamma + (size_t)l * D, beta + (size_t)l * D,
                W2 + (size_t)l * D * D, b2 + (size_t)l * D, hbuf);
            hcur = hbuf;
        }
    }

    pool_cls_kernel<<<G, 128, 0, stream>>>(
        hbuf, batch, Wc1, bc1, Wc2, bc2, (float*)d_out, N);
}

// Round 5
// 1623.421 us; speedup vs baseline: 1.1191x; 1.0260x over previous
//
#include <hip/hip_runtime.h>
#include <math.h>

#define D   128
#define ED  16
#define LAYERS 3
#define CLS 10
#define NPW 8          // nodes per wave
#define WPB 2          // waves per block
#define NPB (NPW*WPB)  // nodes per block
#define CH  32         // edges per staged chunk
#define SRCPAD 256     // padded tail of src_s (zeroed each launch)

// ===========================================================================
// Preprocessing: build CSR (edges grouped by dst) once per launch.
// ===========================================================================
__global__ __launch_bounds__(256) void hist_kernel(
    const int* __restrict__ dst, int* __restrict__ deg, int E)
{
    for (int e = blockIdx.x * blockDim.x + threadIdx.x; e < E;
         e += gridDim.x * blockDim.x)
        atomicAdd(&deg[dst[e]], 1);
}

__global__ __launch_bounds__(256) void scan_kernel(
    const int* __restrict__ deg, int* __restrict__ row_ptr,
    int* __restrict__ cursor, int N)
{
    __shared__ int part[256];
    const int t = threadIdx.x;
    const int chunk = (N + 255) / 256;
    const int beg = t * chunk;
    const int end = min(beg + chunk, N);

    int s = 0;
    for (int i = beg; i < end; ++i) s += deg[i];
    part[t] = s;
    __syncthreads();
    for (int ofs = 1; ofs < 256; ofs <<= 1) {
        int v = (t >= ofs) ? part[t - ofs] : 0;
        __syncthreads();
        part[t] += v;
        __syncthreads();
    }
    int base = (t == 0) ? 0 : part[t - 1];
    for (int i = beg; i < end; ++i) {
        row_ptr[i] = base;
        cursor[i]  = base;
        base += deg[i];
    }
    if (t == 255) row_ptr[N] = part[255];
}

__global__ __launch_bounds__(256) void scatter_kernel(
    const int* __restrict__ src, const int* __restrict__ dst,
    const float* __restrict__ ea,
    int* __restrict__ cursor,
    int* __restrict__ src_s, float* __restrict__ ea_s, int E)
{
    for (int e = blockIdx.x * blockDim.x + threadIdx.x; e < E;
         e += gridDim.x * blockDim.x) {
        const int pos = atomicAdd(&cursor[dst[e]], 1);
        src_s[pos] = src[e];
        const float4* a = (const float4*)(ea + (size_t)e * ED);
        float4* o = (float4*)(ea_s + (size_t)pos * ED);
        o[0] = a[0]; o[1] = a[1]; o[2] = a[2]; o[3] = a[3];
    }
}

// ===========================================================================
// Aggregation v3: z[n] = h[n] + sum_e relu(h[src]+ea@We+be)
//   - ONE wave owns each node range (8 nodes); lane = 2 adjacent channels
//     (float2) -> each edge is processed by exactly one wave: halves the
//     per-edge LDS-read + overhead instruction stream vs the R4 layout.
//   - ea rows DMA-staged (global_load_lds w16, NT cache policy so the 102MB
//     ea stream doesn't evict the 51MB h array from L3), double-buffered
//     per-wave LDS, counted s_waitcnt vmcnt(2), no __syncthreads.
//   - src_s padded+zeroed -> no min() clamps in the 3-group src lookahead.
//   - h[src] gather = one dwordx2 per edge per lane (512B/wave, coalesced).
// ===========================================================================
__device__ __forceinline__ void stage_chunk(
    const float* __restrict__ ea_s, float* ldsbase, long long ce, int ln)
{
#pragma unroll
    for (int i = 0; i < 2; ++i) {
        const void* gp = (const char*)ea_s + (size_t)ce * 64 + (size_t)i * 1024
                         + (size_t)ln * 16;
        void* lp = (char*)ldsbase + i * 1024;
        __builtin_amdgcn_global_load_lds(
            (const __attribute__((address_space(1))) void*)gp,
            (__attribute__((address_space(3))) void*)lp, 16, 0, 2 /*NT*/);
    }
}

__global__ __launch_bounds__(128, 5) void aggregate_kernel(
    const float* __restrict__ h,
    const float* __restrict__ ea_s,
    const int*   __restrict__ src_s,
    const int*   __restrict__ row_ptr,
    const float* __restrict__ We,   // [16][128] this layer
    const float* __restrict__ be,
    float* __restrict__ z, int N)
{
    __shared__ __align__(16) float ealds[WPB][2][CH * ED];
    const int tid = threadIdx.x;
    const int wv  = tid >> 6;
    const int ln  = tid & 63;
    const int c0  = ln * 2;                  // channel pair (c0, c0+1)

    float2 w[ED];
#pragma unroll
    for (int k = 0; k < ED; ++k) w[k] = *(const float2*)&We[k * D + c0];
    const float2 bias = *(const float2*)&be[c0];

    const int g0 = blockIdx.x * NPB + wv * NPW;
    if (g0 >= N) return;
    const int gN = min(g0 + NPW, N);
    const int E0 = row_ptr[g0];
    const int E1 = row_ptr[gN];

    int   n     = g0;
    int   bound = row_ptr[g0 + 1];
    float ax = 0.f, ay = 0.f;
    float2 hn = *(const float2*)&h[(size_t)g0 * D + c0];

    const int ecnt = E1 - E0;
    if (ecnt > 0) {
        const int nc = (ecnt + CH - 1) / CH;
        float* lds0 = &ealds[wv][0][0];
        float* lds1 = &ealds[wv][1][0];

        stage_chunk(ea_s, lds0, E0, ln);
        #define LDSRC(q, j) src_s[E0 + 4 * (q) + (j)]       // padded, no clamp
        int sC0 = LDSRC(0,0), sC1 = LDSRC(0,1), sC2 = LDSRC(0,2), sC3 = LDSRC(0,3);
        int sA0 = LDSRC(1,0), sA1 = LDSRC(1,1), sA2 = LDSRC(1,2), sA3 = LDSRC(1,3);
        int sB0 = LDSRC(2,0), sB1 = LDSRC(2,1), sB2 = LDSRC(2,2), sB3 = LDSRC(2,3);
        asm volatile("s_waitcnt vmcnt(0)" ::: "memory");
        float2 hv0 = *(const float2*)&h[(size_t)sC0 * D + c0];
        float2 hv1 = *(const float2*)&h[(size_t)sC1 * D + c0];
        float2 hv2 = *(const float2*)&h[(size_t)sC2 * D + c0];
        float2 hv3 = *(const float2*)&h[(size_t)sC3 * D + c0];

        int eo = E0;
        int q  = 0;

        for (int c = 0; c < nc; ++c) {
            __builtin_amdgcn_sched_barrier(0);
            float* nbuf = ((c + 1) & 1) ? lds1 : lds0;
            stage_chunk(ea_s, nbuf, (long long)E0 + (long long)(c + 1) * CH, ln);
            asm volatile("s_waitcnt vmcnt(2)" ::: "memory");
            __builtin_amdgcn_sched_barrier(0);
            float* cbuf = (c & 1) ? lds1 : lds0;

#pragma unroll
            for (int g = 0; g < 8; ++g) {
                // (a) prefetch srcs for group q+3
                int t0 = LDSRC(q + 3, 0), t1 = LDSRC(q + 3, 1),
                    t2 = LDSRC(q + 3, 2), t3 = LDSRC(q + 3, 3);
                // (b) issue h gathers for group q+1
                float2 f0 = *(const float2*)&h[(size_t)sA0 * D + c0];
                float2 f1 = *(const float2*)&h[(size_t)sA1 * D + c0];
                float2 f2 = *(const float2*)&h[(size_t)sA2 * D + c0];
                float2 f3 = *(const float2*)&h[(size_t)sA3 * D + c0];
                // (c) compute the 4 edges of group q
#pragma unroll
                for (int j = 0; j < 4; ++j) {
                    while (eo == bound) {                  // uniform flush
                        *(float2*)&z[(size_t)n * D + c0] =
                            make_float2(ax + hn.x, ay + hn.y);
                        ax = ay = 0.f;
                        ++n;
                        if (n >= gN) bound = 0x7fffffff;
                        else {
                            bound = row_ptr[n + 1];
                            hn = *(const float2*)&h[(size_t)n * D + c0];
                        }
                    }
                    const float4* ep = (const float4*)&cbuf[(g * 4 + j) * ED];
                    float4 a0 = ep[0], a1 = ep[1], a2 = ep[2], a3 = ep[3];
                    float2 hvj = (j == 0) ? hv0 : (j == 1) ? hv1
                               : (j == 2) ? hv2 : hv3;
                    float mx0 = bias.x + hvj.x, mx1 = 0.f;
                    float my0 = bias.y + hvj.y, my1 = 0.f;
                    mx0 += a0.x * w[0].x;  my0 += a0.x * w[0].y;
                    mx1 += a0.y * w[1].x;  my1 += a0.y * w[1].y;
                    mx0 += a0.z * w[2].x;  my0 += a0.z * w[2].y;
                    mx1 += a0.w * w[3].x;  my1 += a0.w * w[3].y;
                    mx0 += a1.x * w[4].x;  my0 += a1.x * w[4].y;
                    mx1 += a1.y * w[5].x;  my1 += a1.y * w[5].y;
                    mx0 += a1.z * w[6].x;  my0 += a1.z * w[6].y;
                    mx1 += a1.w * w[7].x;  my1 += a1.w * w[7].y;
                    mx0 += a2.x * w[8].x;  my0 += a2.x * w[8].y;
                    mx1 += a2.y * w[9].x;  my1 += a2.y * w[9].y;
                    mx0 += a2.z * w[10].x; my0 += a2.z * w[10].y;
                    mx1 += a2.w * w[11].x; my1 += a2.w * w[11].y;
                    mx0 += a3.x * w[12].x; my0 += a3.x * w[12].y;
                    mx1 += a3.y * w[13].x; my1 += a3.y * w[13].y;
                    mx0 += a3.z * w[14].x; my0 += a3.z * w[14].y;
                    mx1 += a3.w * w[15].x; my1 += a3.w * w[15].y;
                    float rx = fmaxf(mx0 + mx1, 0.f);
                    float ry = fmaxf(my0 + my1, 0.f);
                    if (eo < E1) { ax += rx; ay += ry; }   // tail mask
                    ++eo;
                }
                // (d) rotate rings
                hv0 = f0; hv1 = f1; hv2 = f2; hv3 = f3;
                sA0 = sB0; sA1 = sB1; sA2 = sB2; sA3 = sB3;
                sB0 = t0;  sB1 = t1;  sB2 = t2;  sB3 = t3;
                ++q;
            }
        }
        #undef LDSRC
    }

    while (n < gN) {
        *(float2*)&z[(size_t)n * D + c0] = make_float2(ax + hn.x, ay + hn.y);
        ax = ay = 0.f;
        ++n;
        if (n < gN) hn = *(const float2*)&h[(size_t)n * D + c0];
    }
}

// ===========================================================================
// Fallback edge kernel (atomic path) if ws too small for CSR buffers.
// ===========================================================================
__global__ __launch_bounds__(256) void edge_fallback_kernel(
    const float* __restrict__ h,
    const float* __restrict__ ea,
    const float* __restrict__ We,
    const float* __restrict__ be,
    const int*   __restrict__ src,
    const int*   __restrict__ dst,
    float* __restrict__ zbuf,
    int E)
{
    const int d   = threadIdx.x & 127;
    const int sub = threadIdx.x >> 7;
    float w[ED];
#pragma unroll
    for (int k = 0; k < ED; ++k) w[k] = We[k * D + d];
    const float bias = be[d];

    for (int e = blockIdx.x * 2 + sub; e < E; e += gridDim.x * 2) {
        const float4* a4 = (const float4*)(ea + (size_t)e * ED);
        float4 a0 = a4[0], a1 = a4[1], a2 = a4[2], a3 = a4[3];
        const int s = src[e];
        const int t = dst[e];
        float m0 = bias + h[(size_t)s * D + d];
        float m1 = 0.f, m2 = 0.f, m3 = 0.f;
        m0 += a0.x * w[0];  m1 += a0.y * w[1];  m2 += a0.z * w[2];  m3 += a0.w * w[3];
        m0 += a1.x * w[4];  m1 += a1.y * w[5];  m2 += a1.z * w[6];  m3 += a1.w * w[7];
        m0 += a2.x * w[8];  m1 += a2.y * w[9];  m2 += a2.z * w[10]; m3 += a2.w * w[11];
        m0 += a3.x * w[12]; m1 += a3.y * w[13]; m2 += a3.z * w[14]; m3 += a3.w * w[15];
        atomicAdd(&zbuf[(size_t)t * D + d], fmaxf((m0 + m1) + (m2 + m3), 0.0f));
    }
}

// ===========================================================================
// Node MLP: h_out = relu( relu(bn(z @ W1 + b1)) @ W2 + b2 )   (unchanged)
// ===========================================================================
__device__ __forceinline__ int sw_slot(int k, int nq) {
    return (nq ^ (k & 7) ^ ((k >> 3) & 7));
}

__global__ __launch_bounds__(256) void node_kernel(
    const float* __restrict__ zbuf,
    const float* __restrict__ W1, const float* __restrict__ b1,
    const float* __restrict__ gamma, const float* __restrict__ beta,
    const float* __restrict__ W2, const float* __restrict__ b2,
    float* __restrict__ hout)
{
    __shared__ __align__(16) float zs[D * 32];
    __shared__ __align__(16) float ts[D * 32];
    __shared__ __align__(16) float ws[32 * D];

    const int t  = threadIdx.x;
    const int n0 = (t & 7) * 4;
    const int d0 = (t >> 3) * 4;
    const int nb = blockIdx.x * 32;

    const float rstd = 1.0f / sqrtf(1.0f + 1e-5f);
    float4 scv, biv, b2v;
    {
        float4 g4  = *(const float4*)(gamma + d0);
        float4 be4 = *(const float4*)(beta + d0);
        float4 b14 = *(const float4*)(b1 + d0);
        scv.x = rstd * g4.x; scv.y = rstd * g4.y; scv.z = rstd * g4.z; scv.w = rstd * g4.w;
        biv.x = b14.x * scv.x + be4.x; biv.y = b14.y * scv.y + be4.y;
        biv.z = b14.z * scv.z + be4.z; biv.w = b14.w * scv.w + be4.w;
        b2v = *(const float4*)(b2 + d0);
    }

    {
        const float4* zg = (const float4*)(zbuf + (size_t)nb * D);
#pragma unroll
        for (int j = 0; j < 4; ++j) {
            float4 v = zg[t + 256 * j];
            int n = (t + 256 * j) >> 5;
            int k = (t << 2) & 127;
            zs[(k + 0) * 32 + sw_slot(k + 0, n >> 2) * 4 + (n & 3)] = v.x;
            zs[(k + 1) * 32 + sw_slot(k + 1, n >> 2) * 4 + (n & 3)] = v.y;
            zs[(k + 2) * 32 + sw_slot(k + 2, n >> 2) * 4 + (n & 3)] = v.z;
            zs[(k + 3) * 32 + sw_slot(k + 3, n >> 2) * 4 + (n & 3)] = v.w;
        }
    }

    float4 acc[4];
#pragma unroll
    for (int i = 0; i < 4; ++i) acc[i] = make_float4(0.f, 0.f, 0.f, 0.f);

#pragma unroll
    for (int kk = 0; kk < 4; ++kk) {
        __syncthreads();
        {
            const float4* wsrc = (const float4*)(W1 + kk * 32 * D);
            float4* wdst = (float4*)ws;
#pragma unroll
            for (int j = 0; j < 4; ++j) wdst[t + 256 * j] = wsrc[t + 256 * j];
        }
        __syncthreads();
#pragma unroll
        for (int k = 0; k < 32; ++k) {
            const int kg = kk * 32 + k;
            float4 zv = *(const float4*)&zs[kg * 32 + sw_slot(kg, n0 >> 2) * 4];
            float4 wv = *(const float4*)&ws[k * D + d0];
            acc[0].x += zv.x * wv.x; acc[0].y += zv.x * wv.y; acc[0].z += zv.x * wv.z; acc[0].w += zv.x * wv.w;
            acc[1].x += zv.y * wv.x; acc[1].y += zv.y * wv.y; acc[1].z += zv.y * wv.z; acc[1].w += zv.y * wv.w;
            acc[2].x += zv.z * wv.x; acc[2].y += zv.z * wv.y; acc[2].z += zv.z * wv.z; acc[2].w += zv.z * wv.w;
            acc[3].x += zv.w * wv.x; acc[3].y += zv.w * wv.y; acc[3].z += zv.w * wv.z; acc[3].w += zv.w * wv.w;
        }
    }

#pragma unroll
    for (int i = 0; i < 4; ++i) {
        float4 v;
        v.x = fmaxf(acc[i].x * scv.x + biv.x, 0.f);
        v.y = fmaxf(acc[i].y * scv.y + biv.y, 0.f);
        v.z = fmaxf(acc[i].z * scv.z + biv.z, 0.f);
        v.w = fmaxf(acc[i].w * scv.w + biv.w, 0.f);
        acc[i] = v;
    }
    __syncthreads();
#pragma unroll
    for (int j = 0; j < 4; ++j) {
        float4 v;
        v.x = j == 0 ? acc[0].x : j == 1 ? acc[0].y : j == 2 ? acc[0].z : acc[0].w;
        v.y = j == 0 ? acc[1].x : j == 1 ? acc[1].y : j == 2 ? acc[1].z : acc[1].w;
        v.z = j == 0 ? acc[2].x : j == 1 ? acc[2].y : j == 2 ? acc[2].z : acc[2].w;
        v.w = j == 0 ? acc[3].x : j == 1 ? acc[3].y : j == 2 ? acc[3].z : acc[3].w;
        const int kr = d0 + j;
        *(float4*)&ts[kr * 32 + sw_slot(kr, n0 >> 2) * 4] = v;
    }

#pragma unroll
    for (int i = 0; i < 4; ++i) acc[i] = make_float4(0.f, 0.f, 0.f, 0.f);

#pragma unroll
    for (int kk = 0; kk < 4; ++kk) {
        __syncthreads();
        {
            const float4* wsrc = (const float4*)(W2 + kk * 32 * D);
            float4* wdst = (float4*)ws;
#pragma unroll
            for (int j = 0; j < 4; ++j) wdst[t + 256 * j] = wsrc[t + 256 * j];
        }
        __syncthreads();
#pragma unroll
        for (int k = 0; k < 32; ++k) {
            const int kg = kk * 32 + k;
            float4 zv = *(const float4*)&ts[kg * 32 + sw_slot(kg, n0 >> 2) * 4];
            float4 wv = *(const float4*)&ws[k * D + d0];
            acc[0].x += zv.x * wv.x; acc[0].y += zv.x * wv.y; acc[0].z += zv.x * wv.z; acc[0].w += zv.x * wv.w;
            acc[1].x += zv.y * wv.x; acc[1].y += zv.y * wv.y; acc[1].z += zv.y * wv.z; acc[1].w += zv.y * wv.w;
            acc[2].x += zv.z * wv.x; acc[2].y += zv.z * wv.y; acc[2].z += zv.z * wv.z; acc[2].w += zv.z * wv.w;
            acc[3].x += zv.w * wv.x; acc[3].y += zv.w * wv.y; acc[3].z += zv.w * wv.z; acc[3].w += zv.w * wv.w;
        }
    }

#pragma unroll
    for (int i = 0; i < 4; ++i) {
        float4 v;
        v.x = fmaxf(acc[i].x + b2v.x, 0.f);
        v.y = fmaxf(acc[i].y + b2v.y, 0.f);
        v.z = fmaxf(acc[i].z + b2v.z, 0.f);
        v.w = fmaxf(acc[i].w + b2v.w, 0.f);
        *(float4*)&hout[(size_t)(nb + n0 + i) * D + d0] = v;
    }
}

// ===========================================================================
// Pool + classifier (batch sorted -> binary search, atomic-free).
// ===========================================================================
__global__ __launch_bounds__(128) void pool_cls_kernel(
    const float* __restrict__ h,
    const int*   __restrict__ batch,
    const float* __restrict__ Wc1, const float* __restrict__ bc1,
    const float* __restrict__ Wc2, const float* __restrict__ bc2,
    float* __restrict__ out, int N)
{
    const int g = blockIdx.x;
    const int d = threadIdx.x;

    int lo = 0, hi = N;
    while (lo < hi) { int mid = (lo + hi) >> 1; if (batch[mid] < g) lo = mid + 1; else hi = mid; }
    const int start = lo;
    hi = N;
    while (lo < hi) { int mid = (lo + hi) >> 1; if (batch[mid] < g + 1) lo = mid + 1; else hi = mid; }
    const int end = lo;

    float sum = 0.f;
    for (int n = start; n < end; ++n) sum += h[(size_t)n * D + d];

    __shared__ float pooled[D];
    __shared__ float hid[D];
    pooled[d] = sum;
    __syncthreads();

    float acc = bc1[d];
#pragma unroll 8
    for (int k = 0; k < D; ++k) acc += pooled[k] * Wc1[k * D + d];
    hid[d] = fmaxf(acc, 0.f);
    __syncthreads();

    if (d < CLS) {
        float o = bc2[d];
#pragma unroll 8
        for (int j = 0; j < D; ++j) o += hid[j] * Wc2[j * CLS + d];
        out[g * CLS + d] = o;
    }
}

// ===========================================================================
extern "C" void kernel_launch(void* const* d_in, const int* in_sizes, int n_in,
                              void* d_out, int out_size, void* d_ws, size_t ws_size,
                              hipStream_t stream)
{
    const float* x         = (const float*)d_in[0];
    const float* edge_attr = (const float*)d_in[1];
    const float* We        = (const float*)d_in[2];
    const float* be        = (const float*)d_in[3];
    const float* W1        = (const float*)d_in[4];
    const float* b1        = (const float*)d_in[5];
    const float* gamma     = (const float*)d_in[6];
    const float* beta      = (const float*)d_in[7];
    const float* W2        = (const float*)d_in[8];
    const float* b2        = (const float*)d_in[9];
    const float* Wc1       = (const float*)d_in[10];
    const float* bc1       = (const float*)d_in[11];
    const float* Wc2       = (const float*)d_in[12];
    const float* bc2       = (const float*)d_in[13];
    const int*   ei        = (const int*)d_in[14];
    const int*   batch     = (const int*)d_in[15];

    const int N = in_sizes[0] / D;
    const int E = in_sizes[1] / ED;
    const int G = out_size / CLS;

    const int* src = ei;
    const int* dst = ei + E;

    // ---- workspace layout (floats first for 16B alignment) ----
    char* p = (char*)d_ws;
    float* zbuf  = (float*)p;  p += (size_t)N * D * sizeof(float);
    float* hbuf  = (float*)p;  p += (size_t)N * D * sizeof(float);
    float* ea_s  = (float*)p;  p += ((size_t)E * ED + 4096) * sizeof(float); // +64-edge pad
    int*   src_s = (int*)p;    p += (size_t)(E + SRCPAD) * sizeof(int);
    int*   deg   = (int*)p;    p += (size_t)N * sizeof(int);
    int*   cur   = (int*)p;    p += (size_t)N * sizeof(int);
    int*   rowp  = (int*)p;    p += (size_t)(N + 4) * sizeof(int);
    const size_t need = (size_t)(p - (char*)d_ws);

    if (ws_size >= need) {
        // ================= CSR path (atomic-free aggregation) ==============
        hipMemsetAsync(deg, 0, (size_t)N * sizeof(int), stream);
        hipMemsetAsync(src_s + E, 0, SRCPAD * sizeof(int), stream); // zero pad
        hist_kernel<<<1024, 256, 0, stream>>>(dst, deg, E);
        scan_kernel<<<1, 256, 0, stream>>>(deg, rowp, cur, N);
        scatter_kernel<<<2048, 256, 0, stream>>>(src, dst, edge_attr, cur,
                                                 src_s, ea_s, E);

        const float* hcur = x;
        for (int l = 0; l < LAYERS; ++l) {
            aggregate_kernel<<<(N + NPB - 1) / NPB, 128, 0, stream>>>(
                hcur, ea_s, src_s, rowp,
                We + (size_t)l * ED * D, be + (size_t)l * D, zbuf, N);
            node_kernel<<<N / 32, 256, 0, stream>>>(
                zbuf, W1 + (size_t)l * D * D, b1 + (size_t)l * D,
                gamma + (size_t)l * D, beta + (size_t)l * D,
                W2 + (size_t)l * D * D, b2 + (size_t)l * D, hbuf);
            hcur = hbuf;
        }
    } else {
        // ================= fallback: atomic scatter path ===================
        const float* hcur = x;
        for (int l = 0; l < LAYERS; ++l) {
            hipMemcpyAsync(zbuf, hcur, (size_t)N * D * sizeof(float),
                           hipMemcpyDeviceToDevice, stream);
            edge_fallback_kernel<<<2048, 256, 0, stream>>>(
                hcur, edge_attr, We + (size_t)l * ED * D, be + (size_t)l * D,
                src, dst, zbuf, E);
            node_kernel<<<N / 32, 256, 0, stream>>>(
                zbuf, W1 + (size_t)l * D * D, b1 + (size_t)l * D,
                gamma + (size_t)l * D, beta + (size_t)l * D,
                W2 + (size_t)l * D * D, b2 + (size_t)l * D, hbuf);
            hcur = hbuf;
        }
    }

    pool_cls_kernel<<<G, 128, 0, stream>>>(
        hbuf, batch, Wc1, bc1, Wc2, bc2, (float*)d_out, N);
}

// Round 6
// 1274.468 us; speedup vs baseline: 1.4255x; 1.2738x over previous
//
#include <hip/hip_runtime.h>
#include <math.h>

#define D   128
#define ED  16
#define LAYERS 3
#define CLS 10
#define NPW 8          // nodes per wave
#define WPB 2          // waves per block
#define NPB (NPW*WPB)  // nodes per block
#define CH  32         // edges per staged chunk
#define SRCPAD 256     // padded tail of src_s (zeroed each launch)
#define SCAN_CHUNK 1024

// ===========================================================================
// Preprocessing: build CSR (edges grouped by dst) once per launch.
// ===========================================================================
__global__ __launch_bounds__(256) void hist_kernel(
    const int* __restrict__ dst, int* __restrict__ deg, int E)
{
    for (int e = blockIdx.x * blockDim.x + threadIdx.x; e < E;
         e += gridDim.x * blockDim.x)
        atomicAdd(&deg[dst[e]], 1);
}

// ---- parallel scan (3 kernels): deg[N] -> row_ptr[N+1], cursor[N] ----------
__global__ __launch_bounds__(256) void partial_kernel(
    const int* __restrict__ deg, int* __restrict__ partials, int N)
{
    __shared__ int red[256];
    const int b = blockIdx.x, t = threadIdx.x;
    const int base = b * SCAN_CHUNK + t * 4;
    int s = 0;
#pragma unroll
    for (int j = 0; j < 4; ++j) { int i = base + j; if (i < N) s += deg[i]; }
    red[t] = s; __syncthreads();
    for (int o = 128; o > 0; o >>= 1) {
        if (t < o) red[t] += red[t + o];
        __syncthreads();
    }
    if (t == 0) partials[b] = red[0];
}

__global__ __launch_bounds__(256) void scanp_kernel(
    const int* __restrict__ partials, int* __restrict__ scanned, int S)
{
    __shared__ int sh[256];
    const int t = threadIdx.x;
    const int v = (t < S) ? partials[t] : 0;
    sh[t] = v; __syncthreads();
    for (int o = 1; o < 256; o <<= 1) {
        int u = (t >= o) ? sh[t - o] : 0;
        __syncthreads();
        sh[t] += u;
        __syncthreads();
    }
    if (t <= S) scanned[t] = sh[t] - ((t < S) ? partials[t] : 0); // exclusive; scanned[S]=total
}

__global__ __launch_bounds__(256) void emit_kernel(
    const int* __restrict__ deg, const int* __restrict__ scanned,
    int* __restrict__ row_ptr, int* __restrict__ cursor, int N, int S)
{
    __shared__ int sh[256];
    const int b = blockIdx.x, t = threadIdx.x;
    const int base = b * SCAN_CHUNK + t * 4;
    int d0 = 0, d1 = 0, d2 = 0, d3 = 0;
    if (base + 0 < N) d0 = deg[base + 0];
    if (base + 1 < N) d1 = deg[base + 1];
    if (base + 2 < N) d2 = deg[base + 2];
    if (base + 3 < N) d3 = deg[base + 3];
    const int ts = d0 + d1 + d2 + d3;
    sh[t] = ts; __syncthreads();
    for (int o = 1; o < 256; o <<= 1) {
        int u = (t >= o) ? sh[t - o] : 0;
        __syncthreads();
        sh[t] += u;
        __syncthreads();
    }
    int run = scanned[b] + sh[t] - ts;   // exclusive prefix within block + base
    if (base + 0 < N) { row_ptr[base + 0] = run; cursor[base + 0] = run; run += d0; }
    if (base + 1 < N) { row_ptr[base + 1] = run; cursor[base + 1] = run; run += d1; }
    if (base + 2 < N) { row_ptr[base + 2] = run; cursor[base + 2] = run; run += d2; }
    if (base + 3 < N) { row_ptr[base + 3] = run; cursor[base + 3] = run; run += d3; }
    if (b == 0 && t == 0) row_ptr[N] = scanned[S];
}

// fallback single-block scan (only if S > 256; not expected at this size)
__global__ __launch_bounds__(256) void scan_kernel(
    const int* __restrict__ deg, int* __restrict__ row_ptr,
    int* __restrict__ cursor, int N)
{
    __shared__ int part[256];
    const int t = threadIdx.x;
    const int chunk = (N + 255) / 256;
    const int beg = t * chunk;
    const int end = min(beg + chunk, N);
    int s = 0;
    for (int i = beg; i < end; ++i) s += deg[i];
    part[t] = s;
    __syncthreads();
    for (int ofs = 1; ofs < 256; ofs <<= 1) {
        int v = (t >= ofs) ? part[t - ofs] : 0;
        __syncthreads();
        part[t] += v;
        __syncthreads();
    }
    int base = (t == 0) ? 0 : part[t - 1];
    for (int i = beg; i < end; ++i) {
        row_ptr[i] = base; cursor[i] = base; base += deg[i];
    }
    if (t == 255) row_ptr[N] = part[255];
}

__global__ __launch_bounds__(256) void scatter_kernel(
    const int* __restrict__ src, const int* __restrict__ dst,
    const float* __restrict__ ea,
    int* __restrict__ cursor,
    int* __restrict__ src_s, float* __restrict__ ea_s, int E)
{
    for (int e = blockIdx.x * blockDim.x + threadIdx.x; e < E;
         e += gridDim.x * blockDim.x) {
        const int pos = atomicAdd(&cursor[dst[e]], 1);
        src_s[pos] = src[e];
        const float4* a = (const float4*)(ea + (size_t)e * ED);
        float4* o = (float4*)(ea_s + (size_t)pos * ED);
        o[0] = a[0]; o[1] = a[1]; o[2] = a[2]; o[3] = a[3];
    }
}

// ===========================================================================
// Aggregation v4: z[n] = sum_e relu(h[src]+ea@We+be)   (self h added in node)
//   - wave owns 8 nodes, lane = 2 channels (float2)
//   - ea DMA-staged double-buffered per-wave LDS (aux=0: R5's aux=2 NT flag
//     coincided with WRITE_SIZE 50->213MB -- reverted)
//   - h gather pipeline 3 GROUPS deep (ring hA..hD, ~960cy issue-to-use)
//   - boundary s_waitcnt vmcnt(14): keeps 12 h-gathers + 2 stages in flight;
//     chunk-c stage still guaranteed (>=14 VMEM ops issued after it)
// ===========================================================================
__device__ __forceinline__ void stage_chunk(
    const float* __restrict__ ea_s, float* ldsbase, long long ce, int ln)
{
#pragma unroll
    for (int i = 0; i < 2; ++i) {
        const void* gp = (const char*)ea_s + (size_t)ce * 64 + (size_t)i * 1024
                         + (size_t)ln * 16;
        void* lp = (char*)ldsbase + i * 1024;
        __builtin_amdgcn_global_load_lds(
            (const __attribute__((address_space(1))) void*)gp,
            (__attribute__((address_space(3))) void*)lp, 16, 0, 0);
    }
}

__global__ __launch_bounds__(128, 4) void aggregate_kernel(
    const float* __restrict__ h,
    const float* __restrict__ ea_s,
    const int*   __restrict__ src_s,
    const int*   __restrict__ row_ptr,
    const float* __restrict__ We,   // [16][128] this layer
    const float* __restrict__ be,
    float* __restrict__ z, int N)
{
    __shared__ __align__(16) float ealds[WPB][2][CH * ED];
    const int tid = threadIdx.x;
    const int wv  = tid >> 6;
    const int ln  = tid & 63;
    const int c0  = ln * 2;

    float2 w[ED];
#pragma unroll
    for (int k = 0; k < ED; ++k) w[k] = *(const float2*)&We[k * D + c0];
    const float2 bias = *(const float2*)&be[c0];

    const int g0 = blockIdx.x * NPB + wv * NPW;
    if (g0 >= N) return;
    const int gN = min(g0 + NPW, N);
    const int E0 = row_ptr[g0];
    const int E1 = row_ptr[gN];

    int   n     = g0;
    int   bound = row_ptr[g0 + 1];
    float ax = 0.f, ay = 0.f;

    const int ecnt = E1 - E0;
    if (ecnt > 0) {
        const int nc = (ecnt + CH - 1) / CH;
        float* lds0 = &ealds[wv][0][0];
        float* lds1 = &ealds[wv][1][0];

        stage_chunk(ea_s, lds0, E0, ln);
        #define LDSRC(q, j) src_s[E0 + 4 * (q) + (j)]       // padded, no clamp
        // prologue: srcs for groups 0..2 (direct) and 3,4 (ring)
        int r00 = LDSRC(0,0), r01 = LDSRC(0,1), r02 = LDSRC(0,2), r03 = LDSRC(0,3);
        int r10 = LDSRC(1,0), r11 = LDSRC(1,1), r12 = LDSRC(1,2), r13 = LDSRC(1,3);
        int r20 = LDSRC(2,0), r21 = LDSRC(2,1), r22 = LDSRC(2,2), r23 = LDSRC(2,3);
        int sU0 = LDSRC(3,0), sU1 = LDSRC(3,1), sU2 = LDSRC(3,2), sU3 = LDSRC(3,3);
        int sV0 = LDSRC(4,0), sV1 = LDSRC(4,1), sV2 = LDSRC(4,2), sV3 = LDSRC(4,3);
        asm volatile("s_waitcnt vmcnt(0)" ::: "memory");
        // issue h for groups 0,1,2
        float2 hA0 = *(const float2*)&h[(size_t)r00 * D + c0];
        float2 hA1 = *(const float2*)&h[(size_t)r01 * D + c0];
        float2 hA2 = *(const float2*)&h[(size_t)r02 * D + c0];
        float2 hA3 = *(const float2*)&h[(size_t)r03 * D + c0];
        float2 hB0 = *(const float2*)&h[(size_t)r10 * D + c0];
        float2 hB1 = *(const float2*)&h[(size_t)r11 * D + c0];
        float2 hB2 = *(const float2*)&h[(size_t)r12 * D + c0];
        float2 hB3 = *(const float2*)&h[(size_t)r13 * D + c0];
        float2 hC0 = *(const float2*)&h[(size_t)r20 * D + c0];
        float2 hC1 = *(const float2*)&h[(size_t)r21 * D + c0];
        float2 hC2 = *(const float2*)&h[(size_t)r22 * D + c0];
        float2 hC3 = *(const float2*)&h[(size_t)r23 * D + c0];

        int eo = E0;
        int q  = 0;

        for (int c = 0; c < nc; ++c) {
            __builtin_amdgcn_sched_barrier(0);
            float* nbuf = ((c + 1) & 1) ? lds1 : lds0;
            stage_chunk(ea_s, nbuf, (long long)E0 + (long long)(c + 1) * CH, ln);
            asm volatile("s_waitcnt vmcnt(14)" ::: "memory");
            __builtin_amdgcn_sched_barrier(0);
            float* cbuf = (c & 1) ? lds1 : lds0;

#pragma unroll
            for (int g = 0; g < 8; ++g) {
                // (a) prefetch srcs for group q+5
                int p0 = LDSRC(q + 5, 0), p1 = LDSRC(q + 5, 1),
                    p2 = LDSRC(q + 5, 2), p3 = LDSRC(q + 5, 3);
                // (b) issue h gathers for group q+3 (srcs = sU)
                float2 hD0 = *(const float2*)&h[(size_t)sU0 * D + c0];
                float2 hD1 = *(const float2*)&h[(size_t)sU1 * D + c0];
                float2 hD2 = *(const float2*)&h[(size_t)sU2 * D + c0];
                float2 hD3 = *(const float2*)&h[(size_t)sU3 * D + c0];
                // (c) compute the 4 edges of group q (h = hA ring slot)
#pragma unroll
                for (int j = 0; j < 4; ++j) {
                    while (eo == bound) {                  // uniform flush
                        *(float2*)&z[(size_t)n * D + c0] = make_float2(ax, ay);
                        ax = ay = 0.f;
                        ++n;
                        bound = (n >= gN) ? 0x7fffffff : row_ptr[n + 1];
                    }
                    const float4* ep = (const float4*)&cbuf[(g * 4 + j) * ED];
                    float4 a0 = ep[0], a1 = ep[1], a2 = ep[2], a3 = ep[3];
                    float2 hvj = (j == 0) ? hA0 : (j == 1) ? hA1
                               : (j == 2) ? hA2 : hA3;
                    float mx0 = bias.x + hvj.x, mx1 = 0.f;
                    float my0 = bias.y + hvj.y, my1 = 0.f;
                    mx0 += a0.x * w[0].x;  my0 += a0.x * w[0].y;
                    mx1 += a0.y * w[1].x;  my1 += a0.y * w[1].y;
                    mx0 += a0.z * w[2].x;  my0 += a0.z * w[2].y;
                    mx1 += a0.w * w[3].x;  my1 += a0.w * w[3].y;
                    mx0 += a1.x * w[4].x;  my0 += a1.x * w[4].y;
                    mx1 += a1.y * w[5].x;  my1 += a1.y * w[5].y;
                    mx0 += a1.z * w[6].x;  my0 += a1.z * w[6].y;
                    mx1 += a1.w * w[7].x;  my1 += a1.w * w[7].y;
                    mx0 += a2.x * w[8].x;  my0 += a2.x * w[8].y;
                    mx1 += a2.y * w[9].x;  my1 += a2.y * w[9].y;
                    mx0 += a2.z * w[10].x; my0 += a2.z * w[10].y;
                    mx1 += a2.w * w[11].x; my1 += a2.w * w[11].y;
                    mx0 += a3.x * w[12].x; my0 += a3.x * w[12].y;
                    mx1 += a3.y * w[13].x; my1 += a3.y * w[13].y;
                    mx0 += a3.z * w[14].x; my0 += a3.z * w[14].y;
                    mx1 += a3.w * w[15].x; my1 += a3.w * w[15].y;
                    float rx = fmaxf(mx0 + mx1, 0.f);
                    float ry = fmaxf(my0 + my1, 0.f);
                    if (eo < E1) { ax += rx; ay += ry; }   // tail mask
                    ++eo;
                }
                // (d) rotate rings (all static names)
                hA0 = hB0; hA1 = hB1; hA2 = hB2; hA3 = hB3;
                hB0 = hC0; hB1 = hC1; hB2 = hC2; hB3 = hC3;
                hC0 = hD0; hC1 = hD1; hC2 = hD2; hC3 = hD3;
                sU0 = sV0; sU1 = sV1; sU2 = sV2; sU3 = sV3;
                sV0 = p0;  sV1 = p1;  sV2 = p2;  sV3 = p3;
                ++q;
            }
        }
        #undef LDSRC
    }

    while (n < gN) {
        *(float2*)&z[(size_t)n * D + c0] = make_float2(ax, ay);
        ax = ay = 0.f;
        ++n;
    }
}

// ===========================================================================
// Fallback edge kernel (atomic path) if ws too small for CSR buffers.
// NOTE: fallback zbuf is seeded with h (memcpy), and node_kernel gets hadd=null.
// ===========================================================================
__global__ __launch_bounds__(256) void edge_fallback_kernel(
    const float* __restrict__ h,
    const float* __restrict__ ea,
    const float* __restrict__ We,
    const float* __restrict__ be,
    const int*   __restrict__ src,
    const int*   __restrict__ dst,
    float* __restrict__ zbuf,
    int E)
{
    const int d   = threadIdx.x & 127;
    const int sub = threadIdx.x >> 7;
    float w[ED];
#pragma unroll
    for (int k = 0; k < ED; ++k) w[k] = We[k * D + d];
    const float bias = be[d];

    for (int e = blockIdx.x * 2 + sub; e < E; e += gridDim.x * 2) {
        const float4* a4 = (const float4*)(ea + (size_t)e * ED);
        float4 a0 = a4[0], a1 = a4[1], a2 = a4[2], a3 = a4[3];
        const int s = src[e];
        const int t = dst[e];
        float m0 = bias + h[(size_t)s * D + d];
        float m1 = 0.f, m2 = 0.f, m3 = 0.f;
        m0 += a0.x * w[0];  m1 += a0.y * w[1];  m2 += a0.z * w[2];  m3 += a0.w * w[3];
        m0 += a1.x * w[4];  m1 += a1.y * w[5];  m2 += a1.z * w[6];  m3 += a1.w * w[7];
        m0 += a2.x * w[8];  m1 += a2.y * w[9];  m2 += a2.z * w[10]; m3 += a2.w * w[11];
        m0 += a3.x * w[12]; m1 += a3.y * w[13]; m2 += a3.z * w[14]; m3 += a3.w * w[15];
        atomicAdd(&zbuf[(size_t)t * D + d], fmaxf((m0 + m1) + (m2 + m3), 0.0f));
    }
}

// ===========================================================================
// Node MLP: h_out = relu( relu(bn((z[+h]) @ W1 + b1)) @ W2 + b2 )
// hadd != null: z_eff = zbuf + hadd (CSR path, agg writes pure aggregate).
// ===========================================================================
__device__ __forceinline__ int sw_slot(int k, int nq) {
    return (nq ^ (k & 7) ^ ((k >> 3) & 7));
}

__global__ __launch_bounds__(256) void node_kernel(
    const float* __restrict__ zbuf,
    const float* __restrict__ hadd,
    const float* __restrict__ W1, const float* __restrict__ b1,
    const float* __restrict__ gamma, const float* __restrict__ beta,
    const float* __restrict__ W2, const float* __restrict__ b2,
    float* __restrict__ hout)
{
    __shared__ __align__(16) float zs[D * 32];
    __shared__ __align__(16) float ts[D * 32];
    __shared__ __align__(16) float ws[32 * D];

    const int t  = threadIdx.x;
    const int n0 = (t & 7) * 4;
    const int d0 = (t >> 3) * 4;
    const int nb = blockIdx.x * 32;

    const float rstd = 1.0f / sqrtf(1.0f + 1e-5f);
    float4 scv, biv, b2v;
    {
        float4 g4  = *(const float4*)(gamma + d0);
        float4 be4 = *(const float4*)(beta + d0);
        float4 b14 = *(const float4*)(b1 + d0);
        scv.x = rstd * g4.x; scv.y = rstd * g4.y; scv.z = rstd * g4.z; scv.w = rstd * g4.w;
        biv.x = b14.x * scv.x + be4.x; biv.y = b14.y * scv.y + be4.y;
        biv.z = b14.z * scv.z + be4.z; biv.w = b14.w * scv.w + be4.w;
        b2v = *(const float4*)(b2 + d0);
    }

    {
        const float4* zg = (const float4*)(zbuf + (size_t)nb * D);
        const float4* hg = (const float4*)(hadd + (size_t)nb * D);
#pragma unroll
        for (int j = 0; j < 4; ++j) {
            float4 v = zg[t + 256 * j];
            if (hadd) {
                float4 u = hg[t + 256 * j];
                v.x += u.x; v.y += u.y; v.z += u.z; v.w += u.w;
            }
            int n = (t + 256 * j) >> 5;
            int k = (t << 2) & 127;
            zs[(k + 0) * 32 + sw_slot(k + 0, n >> 2) * 4 + (n & 3)] = v.x;
            zs[(k + 1) * 32 + sw_slot(k + 1, n >> 2) * 4 + (n & 3)] = v.y;
            zs[(k + 2) * 32 + sw_slot(k + 2, n >> 2) * 4 + (n & 3)] = v.z;
            zs[(k + 3) * 32 + sw_slot(k + 3, n >> 2) * 4 + (n & 3)] = v.w;
        }
    }

    float4 acc[4];
#pragma unroll
    for (int i = 0; i < 4; ++i) acc[i] = make_float4(0.f, 0.f, 0.f, 0.f);

#pragma unroll
    for (int kk = 0; kk < 4; ++kk) {
        __syncthreads();
        {
            const float4* wsrc = (const float4*)(W1 + kk * 32 * D);
            float4* wdst = (float4*)ws;
#pragma unroll
            for (int j = 0; j < 4; ++j) wdst[t + 256 * j] = wsrc[t + 256 * j];
        }
        __syncthreads();
#pragma unroll
        for (int k = 0; k < 32; ++k) {
            const int kg = kk * 32 + k;
            float4 zv = *(const float4*)&zs[kg * 32 + sw_slot(kg, n0 >> 2) * 4];
            float4 wv = *(const float4*)&ws[k * D + d0];
            acc[0].x += zv.x * wv.x; acc[0].y += zv.x * wv.y; acc[0].z += zv.x * wv.z; acc[0].w += zv.x * wv.w;
            acc[1].x += zv.y * wv.x; acc[1].y += zv.y * wv.y; acc[1].z += zv.y * wv.z; acc[1].w += zv.y * wv.w;
            acc[2].x += zv.z * wv.x; acc[2].y += zv.z * wv.y; acc[2].z += zv.z * wv.z; acc[2].w += zv.z * wv.w;
            acc[3].x += zv.w * wv.x; acc[3].y += zv.w * wv.y; acc[3].z += zv.w * wv.z; acc[3].w += zv.w * wv.w;
        }
    }

#pragma unroll
    for (int i = 0; i < 4; ++i) {
        float4 v;
        v.x = fmaxf(acc[i].x * scv.x + biv.x, 0.f);
        v.y = fmaxf(acc[i].y * scv.y + biv.y, 0.f);
        v.z = fmaxf(acc[i].z * scv.z + biv.z, 0.f);
        v.w = fmaxf(acc[i].w * scv.w + biv.w, 0.f);
        acc[i] = v;
    }
    __syncthreads();
#pragma unroll
    for (int j = 0; j < 4; ++j) {
        float4 v;
        v.x = j == 0 ? acc[0].x : j == 1 ? acc[0].y : j == 2 ? acc[0].z : acc[0].w;
        v.y = j == 0 ? acc[1].x : j == 1 ? acc[1].y : j == 2 ? acc[1].z : acc[1].w;
        v.z = j == 0 ? acc[2].x : j == 1 ? acc[2].y : j == 2 ? acc[2].z : acc[2].w;
        v.w = j == 0 ? acc[3].x : j == 1 ? acc[3].y : j == 2 ? acc[3].z : acc[3].w;
        const int kr = d0 + j;
        *(float4*)&ts[kr * 32 + sw_slot(kr, n0 >> 2) * 4] = v;
    }

#pragma unroll
    for (int i = 0; i < 4; ++i) acc[i] = make_float4(0.f, 0.f, 0.f, 0.f);

#pragma unroll
    for (int kk = 0; kk < 4; ++kk) {
        __syncthreads();
        {
            const float4* wsrc = (const float4*)(W2 + kk * 32 * D);
            float4* wdst = (float4*)ws;
#pragma unroll
            for (int j = 0; j < 4; ++j) wdst[t + 256 * j] = wsrc[t + 256 * j];
        }
        __syncthreads();
#pragma unroll
        for (int k = 0; k < 32; ++k) {
            const int kg = kk * 32 + k;
            float4 zv = *(const float4*)&ts[kg * 32 + sw_slot(kg, n0 >> 2) * 4];
            float4 wv = *(const float4*)&ws[k * D + d0];
            acc[0].x += zv.x * wv.x; acc[0].y += zv.x * wv.y; acc[0].z += zv.x * wv.z; acc[0].w += zv.x * wv.w;
            acc[1].x += zv.y * wv.x; acc[1].y += zv.y * wv.y; acc[1].z += zv.y * wv.z; acc[1].w += zv.y * wv.w;
            acc[2].x += zv.z * wv.x; acc[2].y += zv.z * wv.y; acc[2].z += zv.z * wv.z; acc[2].w += zv.z * wv.w;
            acc[3].x += zv.w * wv.x; acc[3].y += zv.w * wv.y; acc[3].z += zv.w * wv.z; acc[3].w += zv.w * wv.w;
        }
    }

#pragma unroll
    for (int i = 0; i < 4; ++i) {
        float4 v;
        v.x = fmaxf(acc[i].x + b2v.x, 0.f);
        v.y = fmaxf(acc[i].y + b2v.y, 0.f);
        v.z = fmaxf(acc[i].z + b2v.z, 0.f);
        v.w = fmaxf(acc[i].w + b2v.w, 0.f);
        *(float4*)&hout[(size_t)(nb + n0 + i) * D + d0] = v;
    }
}

// ===========================================================================
// Pool + classifier (batch sorted -> binary search, atomic-free).
// ===========================================================================
__global__ __launch_bounds__(128) void pool_cls_kernel(
    const float* __restrict__ h,
    const int*   __restrict__ batch,
    const float* __restrict__ Wc1, const float* __restrict__ bc1,
    const float* __restrict__ Wc2, const float* __restrict__ bc2,
    float* __restrict__ out, int N)
{
    const int g = blockIdx.x;
    const int d = threadIdx.x;

    int lo = 0, hi = N;
    while (lo < hi) { int mid = (lo + hi) >> 1; if (batch[mid] < g) lo = mid + 1; else hi = mid; }
    const int start = lo;
    hi = N;
    while (lo < hi) { int mid = (lo + hi) >> 1; if (batch[mid] < g + 1) lo = mid + 1; else hi = mid; }
    const int end = lo;

    float sum = 0.f;
    for (int n = start; n < end; ++n) sum += h[(size_t)n * D + d];

    __shared__ float pooled[D];
    __shared__ float hid[D];
    pooled[d] = sum;
    __syncthreads();

    float acc = bc1[d];
#pragma unroll 8
    for (int k = 0; k < D; ++k) acc += pooled[k] * Wc1[k * D + d];
    hid[d] = fmaxf(acc, 0.f);
    __syncthreads();

    if (d < CLS) {
        float o = bc2[d];
#pragma unroll 8
        for (int j = 0; j < D; ++j) o += hid[j] * Wc2[j * CLS + d];
        out[g * CLS + d] = o;
    }
}

// ===========================================================================
extern "C" void kernel_launch(void* const* d_in, const int* in_sizes, int n_in,
                              void* d_out, int out_size, void* d_ws, size_t ws_size,
                              hipStream_t stream)
{
    const float* x         = (const float*)d_in[0];
    const float* edge_attr = (const float*)d_in[1];
    const float* We        = (const float*)d_in[2];
    const float* be        = (const float*)d_in[3];
    const float* W1        = (const float*)d_in[4];
    const float* b1        = (const float*)d_in[5];
    const float* gamma     = (const float*)d_in[6];
    const float* beta      = (const float*)d_in[7];
    const float* W2        = (const float*)d_in[8];
    const float* b2        = (const float*)d_in[9];
    const float* Wc1       = (const float*)d_in[10];
    const float* bc1       = (const float*)d_in[11];
    const float* Wc2       = (const float*)d_in[12];
    const float* bc2       = (const float*)d_in[13];
    const int*   ei        = (const int*)d_in[14];
    const int*   batch     = (const int*)d_in[15];

    const int N = in_sizes[0] / D;
    const int E = in_sizes[1] / ED;
    const int G = out_size / CLS;

    const int* src = ei;
    const int* dst = ei + E;

    const int S = (N + SCAN_CHUNK - 1) / SCAN_CHUNK;

    // ---- workspace layout (floats first for 16B alignment) ----
    char* p = (char*)d_ws;
    float* zbuf  = (float*)p;  p += (size_t)N * D * sizeof(float);
    float* hbuf  = (float*)p;  p += (size_t)N * D * sizeof(float);
    float* ea_s  = (float*)p;  p += ((size_t)E * ED + 4096) * sizeof(float); // 256-edge pad
    int*   src_s = (int*)p;    p += (size_t)(E + SRCPAD) * sizeof(int);
    int*   deg   = (int*)p;    p += (size_t)N * sizeof(int);
    int*   cur   = (int*)p;    p += (size_t)N * sizeof(int);
    int*   rowp  = (int*)p;    p += (size_t)(N + 4) * sizeof(int);
    int*   parts = (int*)p;    p += (size_t)(S + 8) * sizeof(int);
    int*   scnd  = (int*)p;    p += (size_t)(S + 8) * sizeof(int);
    const size_t need = (size_t)(p - (char*)d_ws);

    if (ws_size >= need) {
        // ================= CSR path (atomic-free aggregation) ==============
        hipMemsetAsync(deg, 0, (size_t)N * sizeof(int), stream);
        hipMemsetAsync(src_s + E, 0, SRCPAD * sizeof(int), stream);
        hist_kernel<<<1024, 256, 0, stream>>>(dst, deg, E);
        if (S <= 256) {
            partial_kernel<<<S, 256, 0, stream>>>(deg, parts, N);
            scanp_kernel<<<1, 256, 0, stream>>>(parts, scnd, S);
            emit_kernel<<<S, 256, 0, stream>>>(deg, scnd, rowp, cur, N, S);
        } else {
            scan_kernel<<<1, 256, 0, stream>>>(deg, rowp, cur, N);
        }
        scatter_kernel<<<2048, 256, 0, stream>>>(src, dst, edge_attr, cur,
                                                 src_s, ea_s, E);

        const float* hcur = x;
        for (int l = 0; l < LAYERS; ++l) {
            aggregate_kernel<<<(N + NPB - 1) / NPB, 128, 0, stream>>>(
                hcur, ea_s, src_s, rowp,
                We + (size_t)l * ED * D, be + (size_t)l * D, zbuf, N);
            node_kernel<<<N / 32, 256, 0, stream>>>(
                zbuf, hcur, W1 + (size_t)l * D * D, b1 + (size_t)l * D,
                gamma + (size_t)l * D, beta + (size_t)l * D,
                W2 + (size_t)l * D * D, b2 + (size_t)l * D, hbuf);
            hcur = hbuf;
        }
    } else {
        // ================= fallback: atomic scatter path ===================
        const float* hcur = x;
        for (int l = 0; l < LAYERS; ++l) {
            hipMemcpyAsync(zbuf, hcur, (size_t)N * D * sizeof(float),
                           hipMemcpyDeviceToDevice, stream);
            edge_fallback_kernel<<<2048, 256, 0, stream>>>(
                hcur, edge_attr, We + (size_t)l * ED * D, be + (size_t)l * D,
                src, dst, zbuf, E);
            node_kernel<<<N / 32, 256, 0, stream>>>(
                zbuf, nullptr, W1 + (size_t)l * D * D, b1 + (size_t)l * D,
                gamma + (size_t)l * D, beta + (size_t)l * D,
                W2 + (size_t)l * D * D, b2 + (size_t)l * D, hbuf);
            hcur = hbuf;
        }
    }

    pool_cls_kernel<<<G, 128, 0, stream>>>(
        hbuf, batch, Wc1, bc1, Wc2, bc2, (float*)d_out, N);
}